// Round 1
// baseline (1228.417 us; speedup 1.0000x reference)
//
#include <hip/hip_runtime.h>

// Problem dims (QLinear: y = x @ (W_q * scale)^T)
#define M_DIM 8192    // BATCH*SEQ = 4*2048
#define N_DIM 11008   // OUT_F
#define K_DIM 4096    // IN_F

typedef __bf16 bf16x8 __attribute__((ext_vector_type(8)));
typedef float f32x4 __attribute__((ext_vector_type(4)));
typedef unsigned short ushort8 __attribute__((ext_vector_type(8)));

// fp32 -> bf16 round-to-nearest-even
__device__ __forceinline__ unsigned short f2bf(float f) {
  unsigned u = __builtin_bit_cast(unsigned, f);
  u += 0x7fffu + ((u >> 16) & 1u);
  return (unsigned short)(u >> 16);
}

// async global->LDS, 16B per lane (wave-uniform LDS base + lane*16)
__device__ __forceinline__ void async_copy16(const void* g, void* l) {
  __builtin_amdgcn_global_load_lds(
      (const __attribute__((address_space(1))) void*)g,
      (__attribute__((address_space(3))) void*)l, 16, 0, 0);
}

// ---- conversion kernels: 8 elements/thread, fully vectorized ----
__global__ __launch_bounds__(256) void cvt_x_kernel(const float* __restrict__ in,
                                                    unsigned short* __restrict__ outp) {
  const int idx = blockIdx.x * 256 + threadIdx.x;
  const float4* in4 = (const float4*)in;
  float4 a = in4[2 * idx], b = in4[2 * idx + 1];
  ushort8 o;
  o[0] = f2bf(a.x); o[1] = f2bf(a.y); o[2] = f2bf(a.z); o[3] = f2bf(a.w);
  o[4] = f2bf(b.x); o[5] = f2bf(b.y); o[6] = f2bf(b.z); o[7] = f2bf(b.w);
  ((ushort8*)outp)[idx] = o;
}

__global__ __launch_bounds__(256) void cvt_w_kernel(const int* __restrict__ in,
                                                    unsigned short* __restrict__ outp) {
  const int idx = blockIdx.x * 256 + threadIdx.x;
  const int4* in4 = (const int4*)in;
  int4 a = in4[2 * idx], b = in4[2 * idx + 1];
  ushort8 o;  // values 0..15: exact in bf16
  o[0] = f2bf((float)a.x); o[1] = f2bf((float)a.y);
  o[2] = f2bf((float)a.z); o[3] = f2bf((float)a.w);
  o[4] = f2bf((float)b.x); o[5] = f2bf((float)b.y);
  o[6] = f2bf((float)b.z); o[7] = f2bf((float)b.w);
  ((ushort8*)outp)[idx] = o;
}

// ---- main GEMM: 128x128 tile, BK=64, 4 waves (2x2), m97 structure ----
// A = x_bf16 [M][K] row-major, B = W_bf16 [N][K] row-major (both K-contiguous).
__global__ __launch_bounds__(256) void gemm_bf16(
    const unsigned short* __restrict__ A, const unsigned short* __restrict__ B,
    const float* __restrict__ scale, float* __restrict__ out) {
  __shared__ __align__(16) unsigned short As[128 * 64];
  __shared__ __align__(16) unsigned short Bs[128 * 64];

  const int tid = threadIdx.x;
  const int bid = blockIdx.x;
  const int bn = (bid % (N_DIM / 128)) * 128;
  const int bm = (bid / (N_DIM / 128)) * 128;

  const int lane = tid & 63;
  const int wv = tid >> 6;
  const int m0 = (wv >> 1) * 64;   // wave row origin in tile
  const int n0 = (wv & 1) * 64;    // wave col origin in tile
  const int lrow = lane & 15;      // A-row / B-col within 16
  const int kgrp = (lane >> 4) * 8;

  // staging decomposition: issue i covers rows [i*32, i*32+32), 8 lanes/row
  const int srow = tid >> 3;        // 0..31
  const int scol = (tid & 7) * 8;   // k-offset 0..56

  f32x4 acc[4][4] = {};

  for (int k0 = 0; k0 < K_DIM; k0 += 64) {
#pragma unroll
    for (int i = 0; i < 4; ++i) {
      async_copy16(&A[(size_t)(bm + i * 32 + srow) * K_DIM + k0 + scol],
                   &As[i * 2048 + tid * 8]);
      async_copy16(&B[(size_t)(bn + i * 32 + srow) * K_DIM + k0 + scol],
                   &Bs[i * 2048 + tid * 8]);
    }
    __syncthreads();  // compiler drains vmcnt before s_barrier

#pragma unroll
    for (int kk = 0; kk < 2; ++kk) {
      bf16x8 af[4], bfr[4];
#pragma unroll
      for (int i = 0; i < 4; ++i)
        af[i] = *reinterpret_cast<const bf16x8*>(
            &As[(m0 + i * 16 + lrow) * 64 + kk * 32 + kgrp]);
#pragma unroll
      for (int j = 0; j < 4; ++j)
        bfr[j] = *reinterpret_cast<const bf16x8*>(
            &Bs[(n0 + j * 16 + lrow) * 64 + kk * 32 + kgrp]);
#pragma unroll
      for (int i = 0; i < 4; ++i)
#pragma unroll
        for (int j = 0; j < 4; ++j)
          acc[i][j] = __builtin_amdgcn_mfma_f32_16x16x32_bf16(
              af[i], bfr[j], acc[i][j], 0, 0, 0);
    }
    __syncthreads();
  }

  // epilogue: C/D layout col=lane&15, row=(lane>>4)*4+r  [m89-verified]
  const int orow0 = bm + m0 + (lane >> 4) * 4;
  const int ocol0 = bn + n0 + lrow;
#pragma unroll
  for (int j = 0; j < 4; ++j) {
    const int col = ocol0 + j * 16;
    const float s = scale[col];
#pragma unroll
    for (int i = 0; i < 4; ++i) {
      const int r0 = orow0 + i * 16;
#pragma unroll
      for (int r = 0; r < 4; ++r)
        out[(size_t)(r0 + r) * N_DIM + col] = acc[i][j][r] * s;
    }
  }
}

// ---- fallback (only if ws too small): fp32 LDS-tiled, correct but slow ----
__global__ __launch_bounds__(256) void gemm_fallback(
    const float* __restrict__ X, const int* __restrict__ Wq,
    const float* __restrict__ scale, float* __restrict__ out) {
  __shared__ float Xs[64][17];
  __shared__ float Ws[64][17];
  const int tid = threadIdx.x;
  const int tn = blockIdx.x % (N_DIM / 64);
  const int tm = blockIdx.x / (N_DIM / 64);
  const int tr = tid >> 4, tc = tid & 15;
  float acc[4][4] = {};
  for (int k0 = 0; k0 < K_DIM; k0 += 16) {
#pragma unroll
    for (int i = 0; i < 4; ++i) {
      int idx = tid + i * 256;
      int r = idx >> 4, c = idx & 15;
      Xs[r][c] = X[(size_t)(tm * 64 + r) * K_DIM + k0 + c];
      Ws[r][c] = (float)Wq[(size_t)(tn * 64 + r) * K_DIM + k0 + c];
    }
    __syncthreads();
#pragma unroll
    for (int kk = 0; kk < 16; ++kk)
#pragma unroll
      for (int i = 0; i < 4; ++i) {
        float a = Xs[tr * 4 + i][kk];
#pragma unroll
        for (int j = 0; j < 4; ++j) acc[i][j] += a * Ws[tc * 4 + j][kk];
      }
    __syncthreads();
  }
#pragma unroll
  for (int i = 0; i < 4; ++i)
#pragma unroll
    for (int j = 0; j < 4; ++j) {
      int row = tm * 64 + tr * 4 + i, col = tn * 64 + tc * 4 + j;
      out[(size_t)row * N_DIM + col] = acc[i][j] * scale[col];
    }
}

extern "C" void kernel_launch(void* const* d_in, const int* in_sizes, int n_in,
                              void* d_out, int out_size, void* d_ws, size_t ws_size,
                              hipStream_t stream) {
  const float* x = (const float*)d_in[0];
  const int* Wq = (const int*)d_in[1];
  const float* scale = (const float*)d_in[2];
  float* out = (float*)d_out;

  const size_t XN = (size_t)M_DIM * K_DIM;  // 33,554,432
  const size_t WN = (size_t)N_DIM * K_DIM;  // 45,088,768
  const size_t need = (XN + WN) * sizeof(unsigned short);  // 150 MiB

  if (ws_size >= need) {
    unsigned short* xbf = (unsigned short*)d_ws;
    unsigned short* wbf = xbf + XN;
    cvt_x_kernel<<<(unsigned)(XN / 2048), 256, 0, stream>>>(x, xbf);
    cvt_w_kernel<<<(unsigned)(WN / 2048), 256, 0, stream>>>(Wq, wbf);
    gemm_bf16<<<(N_DIM / 128) * (M_DIM / 128), 256, 0, stream>>>(xbf, wbf, scale, out);
  } else {
    gemm_fallback<<<(N_DIM / 64) * (M_DIM / 64), 256, 0, stream>>>(x, Wq, scale, out);
  }
}

// Round 2
// 785.267 us; speedup vs baseline: 1.5643x; 1.5643x over previous
//
#include <hip/hip_runtime.h>

// QLinear: y[b,s,o] = sum_i x[b,s,i] * W_q[o,i] * scale[o]
#define M_DIM 8192    // BATCH*SEQ
#define N_DIM 11008   // OUT_F
#define K_DIM 4096    // IN_F

#define BM 256
#define BN 256
#define BK 64
#define NT (K_DIM / BK)            // 64 K-tiles
#define NBN (N_DIM / BN)           // 43
#define NWG ((M_DIM / BM) * NBN)   // 32*43 = 1376 (divisible by 8)

typedef __bf16 bf16x8 __attribute__((ext_vector_type(8)));
typedef float f32x4 __attribute__((ext_vector_type(4)));
typedef unsigned short ushort8 __attribute__((ext_vector_type(8)));

// fp32 -> bf16 round-to-nearest-even
__device__ __forceinline__ unsigned short f2bf(float f) {
  unsigned u = __builtin_bit_cast(unsigned, f);
  u += 0x7fffu + ((u >> 16) & 1u);
  return (unsigned short)(u >> 16);
}

// async global->LDS, 16B/lane (wave-uniform LDS base + lane*16)
__device__ __forceinline__ void async_copy16(const void* g, void* l) {
  __builtin_amdgcn_global_load_lds(
      (const __attribute__((address_space(1))) void*)g,
      (__attribute__((address_space(3))) void*)l, 16, 0, 0);
}

// ---- conversion kernels ----
__global__ __launch_bounds__(256) void cvt_x_kernel(const float* __restrict__ in,
                                                    unsigned short* __restrict__ outp) {
  const int idx = blockIdx.x * 256 + threadIdx.x;
  const float4* in4 = (const float4*)in;
  float4 a = in4[2 * idx], b = in4[2 * idx + 1];
  ushort8 o;
  o[0] = f2bf(a.x); o[1] = f2bf(a.y); o[2] = f2bf(a.z); o[3] = f2bf(a.w);
  o[4] = f2bf(b.x); o[5] = f2bf(b.y); o[6] = f2bf(b.z); o[7] = f2bf(b.w);
  ((ushort8*)outp)[idx] = o;
}

__global__ __launch_bounds__(256) void cvt_w_kernel(const int* __restrict__ in,
                                                    unsigned short* __restrict__ outp) {
  const int idx = blockIdx.x * 256 + threadIdx.x;
  const int4* in4 = (const int4*)in;
  int4 a = in4[2 * idx], b = in4[2 * idx + 1];
  ushort8 o;  // values 0..15: exact in bf16
  o[0] = f2bf((float)a.x); o[1] = f2bf((float)a.y);
  o[2] = f2bf((float)a.z); o[3] = f2bf((float)a.w);
  o[4] = f2bf((float)b.x); o[5] = f2bf((float)b.y);
  o[6] = f2bf((float)b.z); o[7] = f2bf((float)b.w);
  ((ushort8*)outp)[idx] = o;
}

// Stage one 256x64 A-tile + 256x64 B-tile into LDS (linear dest,
// inverse-swizzled global source; rule #21 both-sides swizzle).
// 8 global_load_lds per thread per tile -> vmcnt +8 per wave.
__device__ __forceinline__ void stage_tile(const unsigned short* __restrict__ A,
                                           const unsigned short* __restrict__ B,
                                           int bm, int bn, int k0,
                                           char* Ab, char* Bb, int tid) {
  const int rl = tid >> 3;                       // row within 64-row group
  const int kb = ((tid & 7) * 16) ^ ((rl & 7) << 4);  // pre-swizzled k-byte
#pragma unroll
  for (int i = 0; i < 4; ++i)
    async_copy16(&A[(size_t)(bm + i * 64 + rl) * K_DIM + k0 + (kb >> 1)],
                 Ab + i * 8192 + tid * 16);
#pragma unroll
  for (int i = 0; i < 4; ++i)
    async_copy16(&B[(size_t)(bn + i * 64 + rl) * K_DIM + k0 + (kb >> 1)],
                 Bb + i * 8192 + tid * 16);
}

// ---- main GEMM: 256x256 tile, BK=64, 8 waves, counted-vmcnt pipeline ----
__global__ __launch_bounds__(512, 2) void gemm_bf16(
    const unsigned short* __restrict__ A, const unsigned short* __restrict__ B,
    const float* __restrict__ scale, float* __restrict__ out) {
  __shared__ __align__(16) unsigned short sm[65536];  // 128 KiB: [A0|B0|A1|B1]
  char* smw = (char*)sm;

  const int tid = threadIdx.x;
  const int lane = tid & 63;
  const int wv = tid >> 6;
  const int wr = wv >> 2, wc = wv & 3;   // 2x4 wave grid
  const int lrow = lane & 15, kg = lane >> 4;
  const int swz = (lrow & 7) << 4;       // read-side XOR key (bytes)

  // T1: bijective XCD swizzle (NWG % 8 == 0)
  int id = blockIdx.x;
  id = (id & 7) * (NWG / 8) + (id >> 3);
  const int bn = (id % NBN) * BN;
  const int bm = (id / NBN) * BM;

  const int arow0 = wr * 128 + lrow;     // A-row of this lane's fragments
  const int brow0 = wc * 64 + lrow;      // B-row (= out col) of fragments

  f32x4 acc[8][4] = {};

  // prologue: 2 tiles in flight (16 loads/wave outstanding)
  stage_tile(A, B, bm, bn, 0, smw, smw + 32768, tid);
  stage_tile(A, B, bm, bn, BK, smw + 65536, smw + 98304, tid);

#pragma unroll 1
  for (int t = 0; t < NT - 1; ++t) {
    const int cur = t & 1;
    const char* Ac = smw + cur * 65536;
    const char* Bc = Ac + 32768;

    // wait for tile t's 8 loads (tile t+1's 8 stay in flight), then sync
    asm volatile("s_waitcnt vmcnt(8)" ::: "memory");
    __builtin_amdgcn_s_barrier();
    __builtin_amdgcn_sched_barrier(0);

    bf16x8 af[2][8], bf[2][4];
#pragma unroll
    for (int kk = 0; kk < 2; ++kk) {
      const int kb = (kk * 64 + kg * 16) ^ swz;
#pragma unroll
      for (int m = 0; m < 8; ++m)
        af[kk][m] = *(const bf16x8*)(Ac + (arow0 + m * 16) * 128 + kb);
#pragma unroll
      for (int n = 0; n < 4; ++n)
        bf[kk][n] = *(const bf16x8*)(Bc + (brow0 + n * 16) * 128 + kb);
    }

    // all reads retired -> safe for everyone to overwrite buf[cur]
    asm volatile("s_waitcnt lgkmcnt(0)" ::: "memory");
    __builtin_amdgcn_sched_barrier(0);
    __builtin_amdgcn_s_barrier();

    if (t + 2 < NT)
      stage_tile(A, B, bm, bn, (t + 2) * BK,
                 smw + cur * 65536, smw + cur * 65536 + 32768, tid);

    __builtin_amdgcn_s_setprio(1);
#pragma unroll
    for (int kk = 0; kk < 2; ++kk)
#pragma unroll
      for (int m = 0; m < 8; ++m)
#pragma unroll
        for (int n = 0; n < 4; ++n)
          acc[m][n] = __builtin_amdgcn_mfma_f32_16x16x32_bf16(
              af[kk][m], bf[kk][n], acc[m][n], 0, 0, 0);
    __builtin_amdgcn_s_setprio(0);
  }

  // final tile (t = NT-1, odd -> buffer 1); only its 8 loads remain
  {
    const char* Ac = smw + 65536;
    const char* Bc = Ac + 32768;
    asm volatile("s_waitcnt vmcnt(0)" ::: "memory");
    __builtin_amdgcn_s_barrier();
    __builtin_amdgcn_sched_barrier(0);

    bf16x8 af[2][8], bf[2][4];
#pragma unroll
    for (int kk = 0; kk < 2; ++kk) {
      const int kb = (kk * 64 + kg * 16) ^ swz;
#pragma unroll
      for (int m = 0; m < 8; ++m)
        af[kk][m] = *(const bf16x8*)(Ac + (arow0 + m * 16) * 128 + kb);
#pragma unroll
      for (int n = 0; n < 4; ++n)
        bf[kk][n] = *(const bf16x8*)(Bc + (brow0 + n * 16) * 128 + kb);
    }
    __builtin_amdgcn_s_setprio(1);
#pragma unroll
    for (int kk = 0; kk < 2; ++kk)
#pragma unroll
      for (int m = 0; m < 8; ++m)
#pragma unroll
        for (int n = 0; n < 4; ++n)
          acc[m][n] = __builtin_amdgcn_mfma_f32_16x16x32_bf16(
              af[kk][m], bf[kk][n], acc[m][n], 0, 0, 0);
    __builtin_amdgcn_s_setprio(0);
  }

  // epilogue: C/D layout col=lane&15, row=(lane>>4)*4+r  [m89-verified]
  const int orow = bm + wr * 128 + kg * 4;
  const int ocol = bn + wc * 64 + lrow;
#pragma unroll
  for (int n = 0; n < 4; ++n) {
    const float s = scale[ocol + n * 16];
#pragma unroll
    for (int m = 0; m < 8; ++m) {
#pragma unroll
      for (int r = 0; r < 4; ++r)
        out[(size_t)(orow + m * 16 + r) * N_DIM + ocol + n * 16] =
            acc[m][n][r] * s;
    }
  }
}

// ---- fallback (only if ws too small): fp32 LDS-tiled, correct but slow ----
__global__ __launch_bounds__(256) void gemm_fallback(
    const float* __restrict__ X, const int* __restrict__ Wq,
    const float* __restrict__ scale, float* __restrict__ out) {
  __shared__ float Xs[64][17];
  __shared__ float Ws[64][17];
  const int tid = threadIdx.x;
  const int tn = blockIdx.x % (N_DIM / 64);
  const int tm = blockIdx.x / (N_DIM / 64);
  const int tr = tid >> 4, tc = tid & 15;
  float acc[4][4] = {};
  for (int k0 = 0; k0 < K_DIM; k0 += 16) {
#pragma unroll
    for (int i = 0; i < 4; ++i) {
      int idx = tid + i * 256;
      int r = idx >> 4, c = idx & 15;
      Xs[r][c] = X[(size_t)(tm * 64 + r) * K_DIM + k0 + c];
      Ws[r][c] = (float)Wq[(size_t)(tn * 64 + r) * K_DIM + k0 + c];
    }
    __syncthreads();
#pragma unroll
    for (int kk = 0; kk < 16; ++kk)
#pragma unroll
      for (int i = 0; i < 4; ++i) {
        float a = Xs[tr * 4 + i][kk];
#pragma unroll
        for (int j = 0; j < 4; ++j) acc[i][j] += a * Ws[tc * 4 + j][kk];
      }
    __syncthreads();
  }
#pragma unroll
  for (int i = 0; i < 4; ++i)
#pragma unroll
    for (int j = 0; j < 4; ++j) {
      int row = tm * 64 + tr * 4 + i, col = tn * 64 + tc * 4 + j;
      out[(size_t)row * N_DIM + col] = acc[i][j] * scale[col];
    }
}

extern "C" void kernel_launch(void* const* d_in, const int* in_sizes, int n_in,
                              void* d_out, int out_size, void* d_ws, size_t ws_size,
                              hipStream_t stream) {
  const float* x = (const float*)d_in[0];
  const int* Wq = (const int*)d_in[1];
  const float* scale = (const float*)d_in[2];
  float* out = (float*)d_out;

  const size_t XN = (size_t)M_DIM * K_DIM;
  const size_t WN = (size_t)N_DIM * K_DIM;
  const size_t need = (XN + WN) * sizeof(unsigned short);

  if (ws_size >= need) {
    unsigned short* xbf = (unsigned short*)d_ws;
    unsigned short* wbf = xbf + XN;
    cvt_x_kernel<<<(unsigned)(XN / 2048), 256, 0, stream>>>(x, xbf);
    cvt_w_kernel<<<(unsigned)(WN / 2048), 256, 0, stream>>>(Wq, wbf);
    gemm_bf16<<<NWG, 512, 0, stream>>>(xbf, wbf, scale, out);
  } else {
    gemm_fallback<<<(N_DIM / 64) * (M_DIM / 64), 256, 0, stream>>>(x, Wq, scale, out);
  }
}

// Round 3
// 771.509 us; speedup vs baseline: 1.5922x; 1.0178x over previous
//
#include <hip/hip_runtime.h>

// QLinear: y[b,s,o] = sum_i x[b,s,i] * W_q[o,i] * scale[o]
#define M_DIM 8192    // BATCH*SEQ
#define N_DIM 11008   // OUT_F
#define K_DIM 4096    // IN_F

#define BM 256
#define BN 256
#define BK 64
#define NT (K_DIM / BK)            // 64 K-tiles
#define NBN (N_DIM / BN)           // 43
#define NWG ((M_DIM / BM) * NBN)   // 1376 (divisible by 8)

typedef __bf16 bf16x8 __attribute__((ext_vector_type(8)));
typedef float f32x4 __attribute__((ext_vector_type(4)));
typedef unsigned short ushort8 __attribute__((ext_vector_type(8)));

__device__ __forceinline__ unsigned short f2bf(float f) {
  unsigned u = __builtin_bit_cast(unsigned, f);
  u += 0x7fffu + ((u >> 16) & 1u);
  return (unsigned short)(u >> 16);
}

__device__ __forceinline__ void async_copy16(const void* g, void* l) {
  __builtin_amdgcn_global_load_lds(
      (const __attribute__((address_space(1))) void*)g,
      (__attribute__((address_space(3))) void*)l, 16, 0, 0);
}

// ---- conversion kernels ----
__global__ __launch_bounds__(256) void cvt_x_kernel(const float* __restrict__ in,
                                                    unsigned short* __restrict__ outp) {
  const int idx = blockIdx.x * 256 + threadIdx.x;
  const float4* in4 = (const float4*)in;
  float4 a = in4[2 * idx], b = in4[2 * idx + 1];
  ushort8 o;
  o[0] = f2bf(a.x); o[1] = f2bf(a.y); o[2] = f2bf(a.z); o[3] = f2bf(a.w);
  o[4] = f2bf(b.x); o[5] = f2bf(b.y); o[6] = f2bf(b.z); o[7] = f2bf(b.w);
  ((ushort8*)outp)[idx] = o;
}

__global__ __launch_bounds__(256) void cvt_w_kernel(const int* __restrict__ in,
                                                    unsigned short* __restrict__ outp) {
  const int idx = blockIdx.x * 256 + threadIdx.x;
  const int4* in4 = (const int4*)in;
  int4 a = in4[2 * idx], b = in4[2 * idx + 1];
  ushort8 o;  // values 0..15: exact in bf16
  o[0] = f2bf((float)a.x); o[1] = f2bf((float)a.y);
  o[2] = f2bf((float)a.z); o[3] = f2bf((float)a.w);
  o[4] = f2bf((float)b.x); o[5] = f2bf((float)b.y);
  o[6] = f2bf((float)b.z); o[7] = f2bf((float)b.w);
  ((ushort8*)outp)[idx] = o;
}

// Stage one 128x64 half-tile (16 KiB) into LDS: linear dest, inverse-swizzled
// global source (rule #21). 2 global_load_lds per thread -> vmcnt +2.
__device__ __forceinline__ void stage_half(const unsigned short* __restrict__ P,
                                           int grow0, int k0, char* dest, int tid) {
  const int rl = tid >> 3;                            // 0..63
  const int kb = ((tid & 7) * 16) ^ ((rl & 7) << 4);  // pre-swizzled k-byte
  async_copy16(&P[(size_t)(grow0 + rl) * K_DIM + k0 + (kb >> 1)], dest + tid * 16);
  async_copy16(&P[(size_t)(grow0 + 64 + rl) * K_DIM + k0 + (kb >> 1)],
               dest + 8192 + tid * 16);
}

// ---- main GEMM: 256x256, BK=64, 8 waves, 4-phase/K-tile counted-vmcnt ----
// LDS per buffer: Ah0 +0, Ah1 +16k, Bh0 +32k, Bh1 +48k. Two buffers (128 KiB).
__global__ __launch_bounds__(512, 2) void gemm_bf16(
    const unsigned short* __restrict__ A, const unsigned short* __restrict__ B,
    const float* __restrict__ scale, float* __restrict__ out) {
  __shared__ __align__(16) unsigned short sm[65536];
  char* smw = (char*)sm;

  const int tid = threadIdx.x;
  const int lane = tid & 63;
  const int wv = tid >> 6;
  const int wr = wv >> 2, wc = wv & 3;   // 2x4 wave grid, 128x64 out/wave
  const int lrow = lane & 15, kg = lane >> 4;
  const int swz = (lrow & 7) << 4;       // read-side XOR key (bytes)

  int id = blockIdx.x;                   // T1: bijective XCD swizzle
  id = (id & 7) * (NWG / 8) + (id >> 3);
  const int bn = (id % NBN) * BN;
  const int bm = (id / NBN) * BM;

  const int brow0 = (wc & 1) * 64 + lrow;  // B row within its half

  f32x4 acc[8][4] = {};

  // prologue: tile0 fully (8 loads) + tile1 B-halves (4 loads)
  stage_half(B, bn +   0,  0, smw + 32768, tid);
  stage_half(B, bn + 128,  0, smw + 49152, tid);
  stage_half(A, bm +   0,  0, smw +     0, tid);
  stage_half(A, bm + 128,  0, smw + 16384, tid);
  stage_half(B, bn +   0, BK, smw + 65536 + 32768, tid);
  stage_half(B, bn + 128, BK, smw + 65536 + 49152, tid);
  asm volatile("s_waitcnt vmcnt(4)" ::: "memory");  // tile0 landed
  __builtin_amdgcn_s_barrier();

  bf16x8 af[2][4], bl[2][2], bh[2][2];

#pragma unroll 1
  for (int t = 0; t < NT; ++t) {
    const int cur = t & 1;
    const char* Abuf = smw + cur * 65536 + wr * 16384;
    const char* Bbuf = smw + cur * 65536 + 32768 + (wc >> 1) * 16384;
    char* nbufA = smw + (cur ^ 1) * 65536;           // tile t+1 A dest
    char* cbufB = smw + cur * 65536 + 32768;         // tile t+2 B dest
    const int k1 = (t + 1) * BK, k2 = (t + 2) * BK;

    // ---- P1: read A m0..3 + B n0..1 (12 reads); stage Ah0(t+1)
#pragma unroll
    for (int kk = 0; kk < 2; ++kk) {
      const int kb = (kk * 64 + kg * 16) ^ swz;
#pragma unroll
      for (int m = 0; m < 4; ++m)
        af[kk][m] = *(const bf16x8*)(Abuf + (m * 16 + lrow) * 128 + kb);
#pragma unroll
      for (int n = 0; n < 2; ++n)
        bl[kk][n] = *(const bf16x8*)(Bbuf + (brow0 + n * 16) * 128 + kb);
    }
    if (t + 1 < NT) stage_half(A, bm, k1, nbufA, tid);
    asm volatile("s_waitcnt lgkmcnt(8)" ::: "memory");
    __builtin_amdgcn_s_barrier();
    asm volatile("s_waitcnt lgkmcnt(0)" ::: "memory");
    __builtin_amdgcn_s_setprio(1);
#pragma unroll
    for (int kk = 0; kk < 2; ++kk)
#pragma unroll
      for (int m = 0; m < 4; ++m)
#pragma unroll
        for (int n = 0; n < 2; ++n)
          acc[m][n] = __builtin_amdgcn_mfma_f32_16x16x32_bf16(
              af[kk][m], bl[kk][n], acc[m][n], 0, 0, 0);
    __builtin_amdgcn_s_setprio(0);
    __builtin_amdgcn_s_barrier();

    // ---- P2: read B n2..3 (4 reads); stage Ah1(t+1)
#pragma unroll
    for (int kk = 0; kk < 2; ++kk) {
      const int kb = (kk * 64 + kg * 16) ^ swz;
#pragma unroll
      for (int n = 0; n < 2; ++n)
        bh[kk][n] = *(const bf16x8*)(Bbuf + (brow0 + (n + 2) * 16) * 128 + kb);
    }
    if (t + 1 < NT) stage_half(A, bm + 128, k1, nbufA + 16384, tid);
    __builtin_amdgcn_s_barrier();
    asm volatile("s_waitcnt lgkmcnt(0)" ::: "memory");
    __builtin_amdgcn_s_setprio(1);
#pragma unroll
    for (int kk = 0; kk < 2; ++kk)
#pragma unroll
      for (int m = 0; m < 4; ++m)
#pragma unroll
        for (int n = 0; n < 2; ++n)
          acc[m][n + 2] = __builtin_amdgcn_mfma_f32_16x16x32_bf16(
              af[kk][m], bh[kk][n], acc[m][n + 2], 0, 0, 0);
    __builtin_amdgcn_s_setprio(0);
    __builtin_amdgcn_s_barrier();

    // ---- P3: read A m4..7 (8 reads); stage Bh0(t+2)
#pragma unroll
    for (int kk = 0; kk < 2; ++kk) {
      const int kb = (kk * 64 + kg * 16) ^ swz;
#pragma unroll
      for (int m = 0; m < 4; ++m)
        af[kk][m] = *(const bf16x8*)(Abuf + (64 + m * 16 + lrow) * 128 + kb);
    }
    if (t + 2 < NT) stage_half(B, bn, k2, cbufB, tid);
    __builtin_amdgcn_s_barrier();
    asm volatile("s_waitcnt lgkmcnt(0)" ::: "memory");
    __builtin_amdgcn_s_setprio(1);
#pragma unroll
    for (int kk = 0; kk < 2; ++kk)
#pragma unroll
      for (int m = 0; m < 4; ++m)
#pragma unroll
        for (int n = 0; n < 2; ++n)
          acc[m + 4][n] = __builtin_amdgcn_mfma_f32_16x16x32_bf16(
              af[kk][m], bl[kk][n], acc[m + 4][n], 0, 0, 0);
    __builtin_amdgcn_s_setprio(0);
    __builtin_amdgcn_s_barrier();

    // ---- P4: no reads; stage Bh1(t+2); counted vmcnt closes the tile
    if (t + 2 < NT) stage_half(B, bn + 128, k2, cbufB + 16384, tid);
    __builtin_amdgcn_s_barrier();
    __builtin_amdgcn_s_setprio(1);
#pragma unroll
    for (int kk = 0; kk < 2; ++kk)
#pragma unroll
      for (int m = 0; m < 4; ++m)
#pragma unroll
        for (int n = 0; n < 2; ++n)
          acc[m + 4][n + 2] = __builtin_amdgcn_mfma_f32_16x16x32_bf16(
              af[kk][m], bh[kk][n], acc[m + 4][n + 2], 0, 0, 0);
    __builtin_amdgcn_s_setprio(0);
    if (t + 2 < NT) {
      asm volatile("s_waitcnt vmcnt(4)" ::: "memory");  // tile t+1 landed
      __builtin_amdgcn_s_barrier();
    } else if (t + 1 < NT) {
      asm volatile("s_waitcnt vmcnt(0)" ::: "memory");  // tail drain
      __builtin_amdgcn_s_barrier();
    }
  }

  // epilogue: C/D layout col=lane&15, row=(lane>>4)*4+r  [m89-verified]
  const int orow = bm + wr * 128 + kg * 4;
  const int ocol = bn + wc * 64 + lrow;
#pragma unroll
  for (int n = 0; n < 4; ++n) {
    const float s = scale[ocol + n * 16];
#pragma unroll
    for (int m = 0; m < 8; ++m) {
#pragma unroll
      for (int r = 0; r < 4; ++r)
        out[(size_t)(orow + m * 16 + r) * N_DIM + ocol + n * 16] =
            acc[m][n][r] * s;
    }
  }
}

// ---- fallback (only if ws too small): fp32 LDS-tiled, correct but slow ----
__global__ __launch_bounds__(256) void gemm_fallback(
    const float* __restrict__ X, const int* __restrict__ Wq,
    const float* __restrict__ scale, float* __restrict__ out) {
  __shared__ float Xs[64][17];
  __shared__ float Ws[64][17];
  const int tid = threadIdx.x;
  const int tn = blockIdx.x % (N_DIM / 64);
  const int tm = blockIdx.x / (N_DIM / 64);
  const int tr = tid >> 4, tc = tid & 15;
  float acc[4][4] = {};
  for (int k0 = 0; k0 < K_DIM; k0 += 16) {
#pragma unroll
    for (int i = 0; i < 4; ++i) {
      int idx = tid + i * 256;
      int r = idx >> 4, c = idx & 15;
      Xs[r][c] = X[(size_t)(tm * 64 + r) * K_DIM + k0 + c];
      Ws[r][c] = (float)Wq[(size_t)(tn * 64 + r) * K_DIM + k0 + c];
    }
    __syncthreads();
#pragma unroll
    for (int kk = 0; kk < 16; ++kk)
#pragma unroll
      for (int i = 0; i < 4; ++i) {
        float a = Xs[tr * 4 + i][kk];
#pragma unroll
        for (int j = 0; j < 4; ++j) acc[i][j] += a * Ws[tc * 4 + j][kk];
      }
    __syncthreads();
  }
#pragma unroll
  for (int i = 0; i < 4; ++i)
#pragma unroll
    for (int j = 0; j < 4; ++j) {
      int row = tm * 64 + tr * 4 + i, col = tn * 64 + tc * 4 + j;
      out[(size_t)row * N_DIM + col] = acc[i][j] * scale[col];
    }
}

extern "C" void kernel_launch(void* const* d_in, const int* in_sizes, int n_in,
                              void* d_out, int out_size, void* d_ws, size_t ws_size,
                              hipStream_t stream) {
  const float* x = (const float*)d_in[0];
  const int* Wq = (const int*)d_in[1];
  const float* scale = (const float*)d_in[2];
  float* out = (float*)d_out;

  const size_t XN = (size_t)M_DIM * K_DIM;
  const size_t WN = (size_t)N_DIM * K_DIM;
  const size_t need = (XN + WN) * sizeof(unsigned short);

  if (ws_size >= need) {
    unsigned short* xbf = (unsigned short*)d_ws;
    unsigned short* wbf = xbf + XN;
    cvt_x_kernel<<<(unsigned)(XN / 2048), 256, 0, stream>>>(x, xbf);
    cvt_w_kernel<<<(unsigned)(WN / 2048), 256, 0, stream>>>(Wq, wbf);
    gemm_bf16<<<NWG, 512, 0, stream>>>(xbf, wbf, scale, out);
  } else {
    gemm_fallback<<<(N_DIM / 64) * (M_DIM / 64), 256, 0, stream>>>(x, Wq, scale, out);
  }
}

// Round 5
// 754.195 us; speedup vs baseline: 1.6288x; 1.0230x over previous
//
#include <hip/hip_runtime.h>

// QLinear: y[b,s,o] = sum_i x[b,s,i] * W_q[o,i] * scale[o]
#define M_DIM 8192    // BATCH*SEQ
#define N_DIM 11008   // OUT_F
#define K_DIM 4096    // IN_F

#define BM 256
#define BN 256
#define BK 64
#define NT (K_DIM / BK)            // 64 K-tiles
#define NBN (N_DIM / BN)           // 43
#define NWG ((M_DIM / BM) * NBN)   // 1376 (divisible by 8)

typedef __bf16 bf16x8 __attribute__((ext_vector_type(8)));
typedef float f32x4 __attribute__((ext_vector_type(4)));
typedef unsigned short ushort8 __attribute__((ext_vector_type(8)));

__device__ __forceinline__ unsigned short f2bf(float f) {
  unsigned u = __builtin_bit_cast(unsigned, f);
  u += 0x7fffu + ((u >> 16) & 1u);
  return (unsigned short)(u >> 16);
}

__device__ __forceinline__ void async_copy16(const void* g, void* l) {
  __builtin_amdgcn_global_load_lds(
      (const __attribute__((address_space(1))) void*)g,
      (__attribute__((address_space(3))) void*)l, 16, 0, 0);
}

// ---- conversion kernels ----
__global__ __launch_bounds__(256) void cvt_x_kernel(const float* __restrict__ in,
                                                    unsigned short* __restrict__ outp) {
  const int idx = blockIdx.x * 256 + threadIdx.x;
  const float4* in4 = (const float4*)in;
  float4 a = in4[2 * idx], b = in4[2 * idx + 1];
  ushort8 o;
  o[0] = f2bf(a.x); o[1] = f2bf(a.y); o[2] = f2bf(a.z); o[3] = f2bf(a.w);
  o[4] = f2bf(b.x); o[5] = f2bf(b.y); o[6] = f2bf(b.z); o[7] = f2bf(b.w);
  ((ushort8*)outp)[idx] = o;
}

__global__ __launch_bounds__(256) void cvt_w_kernel(const int* __restrict__ in,
                                                    unsigned short* __restrict__ outp) {
  const int idx = blockIdx.x * 256 + threadIdx.x;
  const int4* in4 = (const int4*)in;
  int4 a = in4[2 * idx], b = in4[2 * idx + 1];
  ushort8 o;  // values 0..15: exact in bf16
  o[0] = f2bf((float)a.x); o[1] = f2bf((float)a.y);
  o[2] = f2bf((float)a.z); o[3] = f2bf((float)a.w);
  o[4] = f2bf((float)b.x); o[5] = f2bf((float)b.y);
  o[6] = f2bf((float)b.z); o[7] = f2bf((float)b.w);
  ((ushort8*)outp)[idx] = o;
}

// Stage one 128x64 half-tile (16 KiB): linear LDS dest, inverse-swizzled
// global source (rule #21 both-sides swizzle). 2 gload_lds -> vmcnt +2.
__device__ __forceinline__ void stage_half(const unsigned short* __restrict__ P,
                                           int grow0, int k0, char* dest, int tid) {
  const int rl = tid >> 3;                            // 0..63
  const int kb = ((tid & 7) * 16) ^ ((rl & 7) << 4);  // pre-swizzled k-byte
  async_copy16(&P[(size_t)(grow0 + rl) * K_DIM + k0 + (kb >> 1)], dest + tid * 16);
  async_copy16(&P[(size_t)(grow0 + 64 + rl) * K_DIM + k0 + (kb >> 1)],
               dest + 8192 + tid * 16);
}

// ---- main GEMM: 256x256, BK=64, 8 waves, 2-phase T3 recipe:
// per tile: issue prefetch(t+1) -> compiler-pipelined 24 ds_read + 64 MFMA
// -> vmcnt(0) BEFORE barrier (cross-wave load visibility) -> barrier. ----
__global__ __launch_bounds__(512, 2) void gemm_bf16(
    const unsigned short* __restrict__ A, const unsigned short* __restrict__ B,
    const float* __restrict__ scale, float* __restrict__ out) {
  __shared__ __align__(16) unsigned short sm[65536];  // 128 KiB, 2 buffers
  char* smw = (char*)sm;

  const int tid = threadIdx.x;
  const int lane = tid & 63;
  const int wv = tid >> 6;
  const int wr = wv >> 2, wc = wv & 3;   // 2x4 wave grid, 128x64 out/wave
  const int lrow = lane & 15, kg = lane >> 4;
  const int swz = (lrow & 7) << 4;       // read-side XOR key (bytes)

  int id = blockIdx.x;                   // T1: bijective XCD swizzle
  id = (id & 7) * (NWG / 8) + (id >> 3);
  const int bn = (id % NBN) * BN;
  const int bm = (id / NBN) * BM;

  const int brow0 = (wc & 1) * 64 + lrow;  // B row within its half

  f32x4 acc[8][4] = {};

  // prologue: stage tile 0 into buffer 0; vmcnt BEFORE barrier (visibility)
  stage_half(A, bm,       0, smw,         tid);
  stage_half(A, bm + 128, 0, smw + 16384, tid);
  stage_half(B, bn,       0, smw + 32768, tid);
  stage_half(B, bn + 128, 0, smw + 49152, tid);
  asm volatile("s_waitcnt vmcnt(0)" ::: "memory");
  __builtin_amdgcn_s_barrier();

#pragma unroll 1
  for (int t = 0; t < NT; ++t) {
    const int cur = t & 1;
    const char* Abuf = smw + cur * 65536 + wr * 16384;
    const char* Bbuf = smw + cur * 65536 + 32768 + (wc >> 1) * 16384;

    // Prefetch tile t+1 into buf[cur^1]. WAR-safe: buf[cur^1]'s readers
    // finished during tile t-1, certified by the bottom barrier of t-1.
    if (t + 1 < NT) {
      char* nb = smw + (cur ^ 1) * 65536;
      const int k1 = (t + 1) * BK;
      stage_half(A, bm,       k1, nb,         tid);
      stage_half(A, bm + 128, k1, nb + 16384, tid);
      stage_half(B, bn,       k1, nb + 32768, tid);
      stage_half(B, bn + 128, k1, nb + 49152, tid);
    }

    // ---- compute: 24 ds_read_b128 + 64 MFMA, compiler-pipelined ----
    bf16x8 af[2][4], bl[2][2], bh[2][2];

    // S1: A m0..3 + B n0..1 (12 reads) -> quadrant (m0-3, n0-1)
#pragma unroll
    for (int kk = 0; kk < 2; ++kk) {
      const int kb = (kk * 64 + kg * 16) ^ swz;
#pragma unroll
      for (int m = 0; m < 4; ++m)
        af[kk][m] = *(const bf16x8*)(Abuf + (m * 16 + lrow) * 128 + kb);
#pragma unroll
      for (int n = 0; n < 2; ++n)
        bl[kk][n] = *(const bf16x8*)(Bbuf + (brow0 + n * 16) * 128 + kb);
    }
#pragma unroll
    for (int kk = 0; kk < 2; ++kk)
#pragma unroll
      for (int m = 0; m < 4; ++m)
#pragma unroll
        for (int n = 0; n < 2; ++n)
          acc[m][n] = __builtin_amdgcn_mfma_f32_16x16x32_bf16(
              af[kk][m], bl[kk][n], acc[m][n], 0, 0, 0);

    // S2: B n2..3 (4 reads) -> quadrant (m0-3, n2-3), reuses af
#pragma unroll
    for (int kk = 0; kk < 2; ++kk) {
      const int kb = (kk * 64 + kg * 16) ^ swz;
#pragma unroll
      for (int n = 0; n < 2; ++n)
        bh[kk][n] = *(const bf16x8*)(Bbuf + (brow0 + (n + 2) * 16) * 128 + kb);
    }
#pragma unroll
    for (int kk = 0; kk < 2; ++kk)
#pragma unroll
      for (int m = 0; m < 4; ++m)
#pragma unroll
        for (int n = 0; n < 2; ++n)
          acc[m][n + 2] = __builtin_amdgcn_mfma_f32_16x16x32_bf16(
              af[kk][m], bh[kk][n], acc[m][n + 2], 0, 0, 0);

    // S3: A m4..7 (8 reads) -> quadrant (m4-7, n0-1), reuses bl
#pragma unroll
    for (int kk = 0; kk < 2; ++kk) {
      const int kb = (kk * 64 + kg * 16) ^ swz;
#pragma unroll
      for (int m = 0; m < 4; ++m)
        af[kk][m] = *(const bf16x8*)(Abuf + (64 + m * 16 + lrow) * 128 + kb);
    }
#pragma unroll
    for (int kk = 0; kk < 2; ++kk)
#pragma unroll
      for (int m = 0; m < 4; ++m)
#pragma unroll
        for (int n = 0; n < 2; ++n)
          acc[m + 4][n] = __builtin_amdgcn_mfma_f32_16x16x32_bf16(
              af[kk][m], bl[kk][n], acc[m + 4][n], 0, 0, 0);

    // S4: no reads -> quadrant (m4-7, n2-3), reuses af+bh
#pragma unroll
    for (int kk = 0; kk < 2; ++kk)
#pragma unroll
      for (int m = 0; m < 4; ++m)
#pragma unroll
        for (int n = 0; n < 2; ++n)
          acc[m + 4][n + 2] = __builtin_amdgcn_mfma_f32_16x16x32_bf16(
              af[kk][m], bh[kk][n], acc[m + 4][n + 2], 0, 0, 0);

    // Bottom sync: drain own prefetch loads (issued a full tile ago ->
    // latency hidden), THEN barrier => all waves' tile-t+1 data visible,
    // and all waves' tile-t LDS reads retired (buf[cur] reusable at t+2).
    if (t + 1 < NT) {
      asm volatile("s_waitcnt vmcnt(0)" ::: "memory");
      __builtin_amdgcn_s_barrier();
    }
  }

  // epilogue: C/D layout col=lane&15, row=(lane>>4)*4+r  [m89-verified]
  const int orow = bm + wr * 128 + kg * 4;
  const int ocol = bn + wc * 64 + lrow;
#pragma unroll
  for (int n = 0; n < 4; ++n) {
    const float s = scale[ocol + n * 16];
#pragma unroll
    for (int m = 0; m < 8; ++m) {
#pragma unroll
      for (int r = 0; r < 4; ++r)
        out[(size_t)(orow + m * 16 + r) * N_DIM + ocol + n * 16] =
            acc[m][n][r] * s;
    }
  }
}

// ---- fallback (only if ws too small): fp32 LDS-tiled, correct but slow ----
__global__ __launch_bounds__(256) void gemm_fallback(
    const float* __restrict__ X, const int* __restrict__ Wq,
    const float* __restrict__ scale, float* __restrict__ out) {
  __shared__ float Xs[64][17];
  __shared__ float Ws[64][17];
  const int tid = threadIdx.x;
  const int tn = blockIdx.x % (N_DIM / 64);
  const int tm = blockIdx.x / (N_DIM / 64);
  const int tr = tid >> 4, tc = tid & 15;
  float acc[4][4] = {};
  for (int k0 = 0; k0 < K_DIM; k0 += 16) {
#pragma unroll
    for (int i = 0; i < 4; ++i) {
      int idx = tid + i * 256;
      int r = idx >> 4, c = idx & 15;
      Xs[r][c] = X[(size_t)(tm * 64 + r) * K_DIM + k0 + c];
      Ws[r][c] = (float)Wq[(size_t)(tn * 64 + r) * K_DIM + k0 + c];
    }
    __syncthreads();
#pragma unroll
    for (int kk = 0; kk < 16; ++kk)
#pragma unroll
      for (int i = 0; i < 4; ++i) {
        float a = Xs[tr * 4 + i][kk];
#pragma unroll
        for (int j = 0; j < 4; ++j) acc[i][j] += a * Ws[tc * 4 + j][kk];
      }
    __syncthreads();
  }
#pragma unroll
  for (int i = 0; i < 4; ++i)
#pragma unroll
    for (int j = 0; j < 4; ++j) {
      int row = tm * 64 + tr * 4 + i, col = tn * 64 + tc * 4 + j;
      out[(size_t)row * N_DIM + col] = acc[i][j] * scale[col];
    }
}

extern "C" void kernel_launch(void* const* d_in, const int* in_sizes, int n_in,
                              void* d_out, int out_size, void* d_ws, size_t ws_size,
                              hipStream_t stream) {
  const float* x = (const float*)d_in[0];
  const int* Wq = (const int*)d_in[1];
  const float* scale = (const float*)d_in[2];
  float* out = (float*)d_out;

  const size_t XN = (size_t)M_DIM * K_DIM;
  const size_t WN = (size_t)N_DIM * K_DIM;
  const size_t need = (XN + WN) * sizeof(unsigned short);

  if (ws_size >= need) {
    unsigned short* xbf = (unsigned short*)d_ws;
    unsigned short* wbf = xbf + XN;
    cvt_x_kernel<<<(unsigned)(XN / 2048), 256, 0, stream>>>(x, xbf);
    cvt_w_kernel<<<(unsigned)(WN / 2048), 256, 0, stream>>>(Wq, wbf);
    gemm_bf16<<<NWG, 512, 0, stream>>>(xbf, wbf, scale, out);
  } else {
    gemm_fallback<<<(N_DIM / 64) * (M_DIM / 64), 256, 0, stream>>>(x, Wq, scale, out);
  }
}